// Round 16
// baseline (190.418 us; speedup 1.0000x reference)
//
#include <hip/hip_runtime.h>

#define NTA 65536
#define NC 1024
#define NO 256
#define HDIM 332
#define HP 352          // H padded to multiple of 32
#define NSP 4
#define NOUT (NTA + NC + NTA*3)   // 263168 f32: en[NTA], E[NC], forces[NTA*3]
#define SORT_CAP (NTA + 4*64)     // 65792 (tiles padded to 64)

// k_main: 64-atom tile, 384 thr (6 waves), 2 blocks/CU (12 waves/CU, 3/SIMD).
// LDS map (dynamic, 57344 B):
//   [0,2048)        wdT    [256] ushort4
//   [2048,51200)    featB  bf16 [64] rows x 512B, XOR-swz (phases 1-2)
//                   dpB    bf16 [64] rows x 768B, XOR-swz (OVERLAY, phases 3-4)
//   [51200,52736)   Epart  [6][64] f32
//   [52736,57344)   Fpart  [6][64][3] f32
#define DP_STRIDE 768
#define LDS_MAIN  57344

typedef __attribute__((ext_vector_type(8))) short short8;
typedef __attribute__((ext_vector_type(4))) float f32x4;

// ---- workspace offsets (bytes) ----
#define OFF_CNT   0
#define OFF_CUR   64
#define OFF_START 128        // 8 ints
#define OFF_FLAG  160        // 1 uint: 1 = float inputs are bf16, 0 = f32
#define OFF_SORT  256        // int[65792] -> ends 263424
#define OFF_B1P   263680     // f32[4*352] -> 269312
#define OFF_W2P   269312     // f32[4*352] -> 274944
#define OFF_W1T   274944     // bf16 [4][352][256] -> 995840
#define OFF_W1P   995840     // bf16 [4][256][352] -> 1716736
#define OFF_FACC  1716736    // f32: forces[196608], Eatom[65536]
#define OFF_ECRY  2765312    // f32[1024]
// end: 2769408

__device__ __forceinline__ unsigned short f2bf(float f){
  unsigned int u = __builtin_bit_cast(unsigned int, f);
  u += 0x7fffu + ((u>>16)&1u);
  return (unsigned short)(u>>16);
}
__device__ __forceinline__ float bf2f(unsigned short h){
  unsigned int u = ((unsigned int)h)<<16;
  return __builtin_bit_cast(float, u);
}
__device__ __forceinline__ float ldf(const void* p, int idx, int isbf){
  if (isbf) return bf2f(((const unsigned short*)p)[idx]);
  return ((const float*)p)[idx];
}
__device__ __forceinline__ float rcpf(float x){ return __builtin_amdgcn_rcpf(x); }

// init: sorted=-1, species count (cnt pre-zeroed via memset), dtype probe
__global__ void k_init2(const int* __restrict__ sym, unsigned int* __restrict__ cnt,
                        int* __restrict__ sorted, const unsigned short* __restrict__ posu,
                        unsigned int* __restrict__ flag){
  __shared__ unsigned int h[NSP];
  int t = threadIdx.x;
  if (t < NSP) h[t] = 0u;
  __syncthreads();
  int i = blockIdx.x*256 + t;
  if (i < SORT_CAP) sorted[i] = -1;
  if (i < NTA) atomicAdd(&h[sym[i]], 1u);
  __syncthreads();
  if (t < NSP && h[t]) atomicAdd(&cnt[t], h[t]);
  if (blockIdx.x == 257 && t < 64){
    unsigned short u = posu[2*t];
    int e = (u>>7)&0xFF;
    bool inr = (e >= 110 && e <= 140);
    unsigned long long m = __ballot(inr);
    if (t == 0) flag[0] = (__popcll(m) >= 32) ? 1u : 0u;
  }
}

// scatter with inline starts computation (64-padded tiles)
__global__ void k_scatter2(const int* __restrict__ sym, const unsigned int* __restrict__ cnt,
                           unsigned int* __restrict__ cur, int* __restrict__ sorted,
                           int* __restrict__ gstarts){
  __shared__ int sl[NSP+1];
  int t = threadIdx.x;
  if (t == 0){
    int a = 0; sl[0] = 0;
    #pragma unroll
    for (int s=0;s<NSP;s++){ a += (int)(((cnt[s]+63u)>>6)<<6); sl[s+1] = a; }
    if (blockIdx.x == 0){
      #pragma unroll
      for (int s=0;s<=NSP;s++) gstarts[s] = sl[s];
    }
  }
  __syncthreads();
  int i = blockIdx.x*256 + t;
  int s = sym[i];
  int lane = t & 63;
  #pragma unroll
  for (int ss=0; ss<NSP; ss++){
    unsigned long long m = __ballot(s==ss);
    if (s == ss){
      int leader = __builtin_ctzll(m);
      int cw = __popcll(m);
      unsigned int b = 0;
      if (lane == leader) b = atomicAdd(&cur[ss], (unsigned int)cw);
      b = (unsigned int)__shfl((int)b, leader);
      int rank = __popcll(m & ((1ull<<lane) - 1ull));
      sorted[sl[ss] + (int)b + rank] = i;
    }
  }
}

// weight prep via 32x32 LDS transpose tiles: coalesced reads AND writes
// grid: 4 species x 11 j-tiles x 8 i-tiles = 352 blocks x 256 thr
__global__ void k_prepw2(const void* __restrict__ W1, const void* __restrict__ b1,
                         const void* __restrict__ W2, const unsigned int* __restrict__ flag,
                         unsigned short* __restrict__ w1t, unsigned short* __restrict__ w1p,
                         float* __restrict__ b1p, float* __restrict__ w2p){
  __shared__ unsigned short T[32][36];
  const int isbf = (int)flag[0];
  const int bid = blockIdx.x;
  const int s  = bid / 88;
  const int jt = (bid % 88) / 8;
  const int it = bid % 8;
  const int t = threadIdx.x;
  {
    const int il = t >> 3;            // 0..31
    const int j4 = (t & 7) * 4;
    const int i = it*32 + il;
    #pragma unroll
    for (int e=0;e<4;e++){
      int j = jt*32 + j4 + e;
      float v = (j < HDIM) ? ldf(W1, (s*NO + i)*HDIM + j, isbf) : 0.f;
      T[il][j4+e] = f2bf(v);
    }
  }
  __syncthreads();
  {
    // w1t[j][i]: 8B per thread, coalesced over i
    const int jl = t >> 3;
    const int i4 = (t & 7) * 4;
    ushort4 v; v.x = T[i4][jl]; v.y = T[i4+1][jl]; v.z = T[i4+2][jl]; v.w = T[i4+3][jl];
    *(ushort4*)&w1t[(s*HP + jt*32 + jl)*NO + it*32 + i4] = v;
    // w1p[i][j]: 8B per thread, coalesced over j
    const int il = t >> 3;
    const int j4 = (t & 7) * 4;
    ushort4 u; u.x = T[il][j4]; u.y = T[il][j4+1]; u.z = T[il][j4+2]; u.w = T[il][j4+3];
    *(ushort4*)&w1p[(s*NO + it*32 + il)*HP + jt*32 + j4] = u;
  }
  if (it == 0 && t < 32){
    int j = jt*32 + t;
    b1p[s*HP + j] = (j < HDIM) ? ldf(b1, s*HDIM + j, isbf) : 0.f;
    w2p[s*HP + j] = (j < HDIM) ? ldf(W2, s*HDIM + j, isbf) : 0.f;
  }
}

// Fused per-tile kernel v6.1: 64-atom tile, 6 waves, 2 blocks/CU (12 waves/CU).
// (v6 NaN fix: phase-1 staging now covers ALL 32 elements per unit — p4 0..3 x 8.)
// GEMM1': pre^T[352][64] = W1T x feat^T, j-frags 4,4,4,4,3,3 -> acc[4][4]=64 regs
// GEMM2': dfeat^T[256][64] = W1P x dpre^T, i-frags 3,3,3,3,2,2 -> acc2[3][4]=48
// dpB overlays featB (stride 768, XOR-swz: max write off 696^112=712<768);
// epilogue2 recomputes tanh. E/F reduced block-locally, plain stores.
// MFMA C/D layout (HW-verified r3 probe): reg q of lane l -> row=(l>>4)*4+q, col=l&15.
__global__ __launch_bounds__(384,3) void k_main(
    const int* __restrict__ sorted, const int* __restrict__ starts,
    const void* __restrict__ pos, const void* __restrict__ Wd,
    const unsigned short* __restrict__ W1T, const unsigned short* __restrict__ W1P,
    const float* __restrict__ b1p, const float* __restrict__ w2p,
    const void* __restrict__ b2g, const int* __restrict__ crys,
    const unsigned int* __restrict__ flag,
    float* __restrict__ Eatom, float* __restrict__ Ecry, float* __restrict__ forces)
{
  extern __shared__ char smem[];
  ushort4* wdT = (ushort4*)smem;            // [256]
  char* featB  = smem + 2048;               // bf16 [64][512B], XOR-swz
  char* dpB    = smem + 2048;               // OVERLAY: bf16 [64][768B], XOR-swz
  float* Epart = (float*)(smem + 51200);    // [6][64]
  float* Fpart = (float*)(smem + 52736);    // [6][64][3]

  const int base = blockIdx.x*64;
  if (base >= starts[4]) return;
  const int isbf = (int)flag[0];
  int sp = 0;
  #pragma unroll
  for (int s=1;s<NSP;s++) sp = (base >= starts[s]) ? s : sp;

  const int tid = threadIdx.x;
  const int l = tid & 63;
  const int w = tid >> 6;       // 0..5
  const int c = l & 15;
  const int g = l >> 4;

  if (tid < 256){
    float x = ldf(Wd, tid, isbf), y = ldf(Wd, NO+tid, isbf), z = ldf(Wd, 2*NO+tid, isbf);
    ushort4 u; u.x = f2bf(x); u.y = f2bf(y); u.z = f2bf(z); u.w = 0;
    wdT[tid] = u;
  }
  __syncthreads();

  // ---- phase 1: stage feat tile; unit = (row m, 32-col chunk q), 512 units ----
  for (int u = tid; u < 512; u += 384){
    const int m = u >> 3;
    const int q = u & 7;
    int a = sorted[base + m];
    float px=0.f, py=0.f, pz=0.f;
    if (a >= 0){ px = ldf(pos,3*a,isbf); py = ldf(pos,3*a+1,isbf); pz = ldf(pos,3*a+2,isbf); }
    const int swz = (m&7)<<4;
    char* rowp = featB + m*512;
    #pragma unroll
    for (int p4=0;p4<4;p4++){
      int i0 = q*32 + p4*8;           // 4 chunks x 8 elements = full 32
      unsigned int pk[4];
      #pragma unroll
      for (int p2=0;p2<4;p2++){
        unsigned short hv[2];
        #pragma unroll
        for (int e2=0;e2<2;e2++){
          ushort4 wv = wdT[i0 + 2*p2 + e2];
          float v = px*bf2f(wv.x) + py*bf2f(wv.y) + pz*bf2f(wv.z);
          float e = __expf(2.f*v);
          hv[e2] = f2bf(1.f - 2.f*rcpf(e+1.f));   // tanh via rcp
        }
        pk[p2] = (unsigned int)hv[0] | ((unsigned int)hv[1]<<16);
      }
      *(uint4*)(rowp + ((i0*2) ^ swz)) = make_uint4(pk[0],pk[1],pk[2],pk[3]);
    }
  }
  __syncthreads();

  // ---- phase 2: GEMM1 (j-frags: 4,4,4,4,3,3) ----
  const unsigned short* W1Ts = W1T + sp*HP*NO;
  const int fr0 = (w<4) ? w*4 : 16 + (w-4)*3;
  const int nT  = (w<4) ? 4 : 3;
  f32x4 acc[4][4];
  #pragma unroll
  for (int t=0;t<4;t++)
    #pragma unroll
    for (int nb=0;nb<4;nb++) acc[t][nb] = f32x4{0.f,0.f,0.f,0.f};

  #pragma unroll
  for (int kk=0; kk<8; kk++){
    short8 bfr[4];
    #pragma unroll
    for (int nb=0;nb<4;nb++){
      int m = nb*16 + c;
      bfr[nb] = *(const short8*)(featB + m*512 + ((kk*64 + g*16) ^ ((m&7)<<4)));
    }
    #pragma unroll
    for (int t=0;t<4;t++){
      if (t < nT){
        const short8 afr = *(const short8*)((const char*)W1Ts + ((fr0+t)*16 + c)*512 + kk*64 + g*16);
        #pragma unroll
        for (int nb=0;nb<4;nb++)
          acc[t][nb] = __builtin_amdgcn_mfma_f32_16x16x32_bf16(afr, bfr[nb], acc[t][nb], 0,0,0);
      }
    }
  }
  __syncthreads();   // all waves done reading featB -> dpB overlay is safe

  // ---- phase 3: epilogue1: silu, E partials, dpre -> dpB (swizzled) ----
  const float* b1s = b1p + sp*HP;
  const float* w2s = w2p + sp*HP;
  float esp[4] = {0.f,0.f,0.f,0.f};
  #pragma unroll
  for (int t=0;t<4;t++){
    if (t < nT){
      const int j0 = (fr0+t)*16 + g*4;
      const float4 b1v = *(const float4*)(b1s + j0);
      const float4 w2v = *(const float4*)(w2s + j0);
      const float* b1a = (const float*)&b1v;
      const float* w2a = (const float*)&w2v;
      #pragma unroll
      for (int nb=0;nb<4;nb++){
        const int m = nb*16 + c;
        unsigned short dph[4];
        #pragma unroll
        for (int q=0;q<4;q++){
          float pre = acc[t][nb][q] + b1a[q];
          float sg = rcpf(1.f + __expf(-pre));     // sigmoid via rcp
          float h = pre*sg;
          esp[nb] += h*w2a[q];
          float dsl = sg*(1.f + pre*(1.f - sg));   // silu'
          dph[q] = f2bf(w2a[q]*dsl);               // dpre
        }
        *(uint2*)(dpB + m*DP_STRIDE + ((j0*2) ^ ((m&7)<<4))) =
            make_uint2((unsigned)dph[0] | ((unsigned)dph[1]<<16),
                       (unsigned)dph[2] | ((unsigned)dph[3]<<16));
      }
    }
  }
  #pragma unroll
  for (int nb=0;nb<4;nb++){
    float e = esp[nb];
    e += __shfl_xor(e, 16);
    e += __shfl_xor(e, 32);
    if (g == 0) Epart[w*64 + nb*16 + c] = e;
  }
  __syncthreads();   // dpB + Epart ready

  // ---- phase 4: GEMM2 (i-frags: 3,3,3,3,2,2) ----
  const unsigned short* W1Ps = W1P + sp*NO*HP;
  const int fr2 = (w<4) ? w*3 : 12 + (w-4)*2;
  const int nT2 = (w<4) ? 3 : 2;
  f32x4 acc2[3][4];
  #pragma unroll
  for (int t2=0;t2<3;t2++)
    #pragma unroll
    for (int nb=0;nb<4;nb++) acc2[t2][nb] = f32x4{0.f,0.f,0.f,0.f};

  #pragma unroll
  for (int kk=0; kk<11; kk++){
    short8 bfr[4];
    #pragma unroll
    for (int nb=0;nb<4;nb++){
      int m = nb*16 + c;
      bfr[nb] = *(const short8*)(dpB + m*DP_STRIDE + ((kk*64 + g*16) ^ ((m&7)<<4)));
    }
    #pragma unroll
    for (int t2=0;t2<3;t2++){
      if (t2 < nT2){
        const short8 afr = *(const short8*)((const char*)W1Ps + ((fr2+t2)*16 + c)*704 + kk*64 + g*16);
        #pragma unroll
        for (int nb=0;nb<4;nb++)
          acc2[t2][nb] = __builtin_amdgcn_mfma_f32_16x16x32_bf16(afr, bfr[nb], acc2[t2][nb], 0,0,0);
      }
    }
  }

  // ---- phase 5: epilogue2: recompute f=tanh; dpos=(dfeat*(1-f^2))@Wd^T ----
  int a4[4]; float px4[4], py4[4], pz4[4];
  #pragma unroll
  for (int nb=0;nb<4;nb++){
    int aa = sorted[base + nb*16 + c];
    a4[nb] = aa;
    float x=0.f,y=0.f,z=0.f;
    if (aa >= 0){ x=ldf(pos,3*aa,isbf); y=ldf(pos,3*aa+1,isbf); z=ldf(pos,3*aa+2,isbf); }
    px4[nb]=x; py4[nb]=y; pz4[nb]=z;
  }
  float fax[4] = {0.f,0.f,0.f,0.f};
  float fay[4] = {0.f,0.f,0.f,0.f};
  float faz[4] = {0.f,0.f,0.f,0.f};
  #pragma unroll
  for (int t2=0;t2<3;t2++){
    if (t2 < nT2){
      const int i0 = (fr2+t2)*16 + g*4;
      #pragma unroll
      for (int q=0;q<4;q++){
        ushort4 wv = wdT[i0 + q];
        float wx = bf2f(wv.x), wy = bf2f(wv.y), wz = bf2f(wv.z);
        #pragma unroll
        for (int nb=0;nb<4;nb++){
          float v = px4[nb]*wx + py4[nb]*wy + pz4[nb]*wz;
          float e = __expf(2.f*v);
          float f = 1.f - 2.f*rcpf(e+1.f);
          float gsc = acc2[t2][nb][q] * (1.f - f*f);
          fax[nb] += gsc*wx;
          fay[nb] += gsc*wy;
          faz[nb] += gsc*wz;
        }
      }
    }
  }
  #pragma unroll
  for (int nb=0;nb<4;nb++){
    float x = fax[nb], y = fay[nb], z = faz[nb];
    x += __shfl_xor(x, 16); x += __shfl_xor(x, 32);
    y += __shfl_xor(y, 16); y += __shfl_xor(y, 32);
    z += __shfl_xor(z, 16); z += __shfl_xor(z, 32);
    if (g == 0){
      const int m = nb*16 + c;
      Fpart[w*192 + m*3 + 0] = x;
      Fpart[w*192 + m*3 + 1] = y;
      Fpart[w*192 + m*3 + 2] = z;
    }
  }
  __syncthreads();

  // ---- final: wave 0 sums 6 partials; plain stores + fused Ecry atomic ----
  if (tid < 64){
    int a = sorted[base + tid];
    if (a >= 0){
      float E = ldf(b2g, sp, isbf);
      float fx = 0.f, fy = 0.f, fz = 0.f;
      #pragma unroll
      for (int ww=0; ww<6; ww++){
        E  += Epart[ww*64 + tid];
        fx += Fpart[ww*192 + tid*3 + 0];
        fy += Fpart[ww*192 + tid*3 + 1];
        fz += Fpart[ww*192 + tid*3 + 2];
      }
      Eatom[a] = E;
      atomicAdd(&Ecry[crys[a]], E);
      forces[3*a+0] = fx;
      forces[3*a+1] = fy;
      forces[3*a+2] = fz;
    }
  }
}

// Output: f32, reference order (energies=en[NTA], energy=E[NC], forces[NTA,3])
__global__ void k_out(const float* __restrict__ Eatom, const float* __restrict__ Ecry,
                      const float* __restrict__ Facc, float* __restrict__ out){
  int i = blockIdx.x*256 + threadIdx.x;   // grid covers 263168 exactly
  float v;
  if (i < NTA)            v = Eatom[i];
  else if (i < NTA + NC)  v = Ecry[i - NTA];
  else                    v = Facc[i - NTA - NC];
  out[i] = v;
}

extern "C" void kernel_launch(void* const* d_in, const int* in_sizes, int n_in,
                              void* d_out, int out_size, void* d_ws, size_t ws_size,
                              hipStream_t stream) {
  const int*   symbols    = (const int*)  d_in[0];
  const void*  positions  = d_in[1];
  // d_in[2] cells, d_in[3] pbcs, d_in[4] energyidx: unused by the math
  const int*   crystalidx = (const int*)  d_in[5];
  const void*  Wd         = d_in[6];
  const void*  W1         = d_in[7];
  const void*  b1         = d_in[8];
  const void*  W2         = d_in[9];
  const void*  b2         = d_in[10];
  float* dout = (float*)d_out;   // f32 output buffer

  char* ws = (char*)d_ws;
  unsigned int* cnt    = (unsigned int*)(ws + OFF_CNT);
  unsigned int* cur    = (unsigned int*)(ws + OFF_CUR);
  int*          starts = (int*)         (ws + OFF_START);
  unsigned int* flag   = (unsigned int*)(ws + OFF_FLAG);
  int*          sorted = (int*)         (ws + OFF_SORT);
  float*        b1p    = (float*)       (ws + OFF_B1P);
  float*        w2p    = (float*)       (ws + OFF_W2P);
  unsigned short* w1t  = (unsigned short*)(ws + OFF_W1T);
  unsigned short* w1pp = (unsigned short*)(ws + OFF_W1P);
  float*        Facc   = (float*)       (ws + OFF_FACC);   // forces[196608]
  float*        Eatom  = Facc + NTA*3;                     // [65536]
  float*        Ecry   = (float*)       (ws + OFF_ECRY);   // [1024]

  hipFuncSetAttribute((const void*)k_main,
                      hipFuncAttributeMaxDynamicSharedMemorySize, LDS_MAIN);

  hipMemsetAsync(ws, 0, 256, stream);                 // cnt/cur/starts/flag
  hipMemsetAsync(ws + OFF_ECRY, 0, NC*4, stream);     // Ecry accumulators
  k_init2   <<<258, 256, 0, stream>>>(symbols, cnt, sorted,
                                      (const unsigned short*)positions, flag);
  k_scatter2<<<256, 256, 0, stream>>>(symbols, cnt, cur, sorted, starts);
  k_prepw2  <<<352, 256, 0, stream>>>(W1, b1, W2, flag, w1t, w1pp, b1p, w2p);
  k_main    <<<1028,384, LDS_MAIN, stream>>>(sorted, starts, positions, Wd,
                                             w1t, w1pp, b1p, w2p, b2, crystalidx,
                                             flag, Eatom, Ecry, Facc);
  k_out     <<<1028,256, 0, stream>>>(Eatom, Ecry, Facc, dout);
}

// Round 17
// 139.081 us; speedup vs baseline: 1.3691x; 1.3691x over previous
//
#include <hip/hip_runtime.h>

#define NTA 65536
#define NC 1024
#define NO 256
#define HDIM 332
#define HP 352          // H padded to multiple of 32
#define NSP 4
#define NOUT (NTA + NC + NTA*3)   // 263168 f32: en[NTA], E[NC], forces[NTA*3]
#define SORT_CAP (NTA + 4*128)    // 66048 (tiles padded to 128)

// k_main: 128-atom tile, 512 thr (8 waves), 1 block/CU (R12 v5 geometry).
// LDS map (dynamic, 159744 B):
//   [0,2048)          wdT    [256] ushort4
//   [2048,67584)      featB  bf16 [128] rows x 512B, XOR-swz
//   [67584,159744)    dpB    bf16 [128] rows x 720B, linear
//                     Epart  [8][128] f32      (OVERLAY dpB after GEMM2)
//                     Fpart  [8][128][3] f32   (OVERLAY dpB+4096)
#define DP_STRIDE 720
#define LDS_MAIN  159744

typedef __attribute__((ext_vector_type(8))) short short8;
typedef __attribute__((ext_vector_type(4))) float f32x4;

// ---- workspace offsets (bytes) ----
#define OFF_CNT   0
#define OFF_CUR   64
#define OFF_START 128        // 8 ints
#define OFF_FLAG  160        // 1 uint: 1 = float inputs are bf16, 0 = f32
#define OFF_SORT  256        // int[66048] -> ends 264448
#define OFF_B1P   264448     // f32[4*352] -> 270080
#define OFF_W2P   270080     // f32[4*352] -> 275712
#define OFF_W1T   275712     // bf16 [4][352][256] -> 996608
#define OFF_W1P   996608     // bf16 [4][256][352] -> 1717504

__device__ __forceinline__ unsigned short f2bf(float f){
  unsigned int u = __builtin_bit_cast(unsigned int, f);
  u += 0x7fffu + ((u>>16)&1u);
  return (unsigned short)(u>>16);
}
__device__ __forceinline__ float bf2f(unsigned short h){
  unsigned int u = ((unsigned int)h)<<16;
  return __builtin_bit_cast(float, u);
}
__device__ __forceinline__ float ldf(const void* p, int idx, int isbf){
  if (isbf) return bf2f(((const unsigned short*)p)[idx]);
  return ((const float*)p)[idx];
}
__device__ __forceinline__ float rcpf(float x){ return __builtin_amdgcn_rcpf(x); }

// init: sorted=-1, species count, dtype probe, zero dout's Ecry slots (replay-safe)
__global__ void k_init2(const int* __restrict__ sym, unsigned int* __restrict__ cnt,
                        int* __restrict__ sorted, const unsigned short* __restrict__ posu,
                        unsigned int* __restrict__ flag, float* __restrict__ dout){
  __shared__ unsigned int h[NSP];
  int t = threadIdx.x;
  if (t < NSP) h[t] = 0u;
  __syncthreads();
  int i = blockIdx.x*256 + t;
  if (i < SORT_CAP) sorted[i] = -1;
  if (i < NC) dout[NTA + i] = 0.f;      // Ecry accumulators live in dout
  if (i < NTA) atomicAdd(&h[sym[i]], 1u);
  __syncthreads();
  if (t < NSP && h[t]) atomicAdd(&cnt[t], h[t]);
  if (blockIdx.x == 257 && t < 64){
    unsigned short u = posu[2*t];
    int e = (u>>7)&0xFF;
    bool inr = (e >= 110 && e <= 140);
    unsigned long long m = __ballot(inr);
    if (t == 0) flag[0] = (__popcll(m) >= 32) ? 1u : 0u;
  }
}

// scatter with inline starts computation (128-padded tiles)
__global__ void k_scatter2(const int* __restrict__ sym, const unsigned int* __restrict__ cnt,
                           unsigned int* __restrict__ cur, int* __restrict__ sorted,
                           int* __restrict__ gstarts){
  __shared__ int sl[NSP+1];
  int t = threadIdx.x;
  if (t == 0){
    int a = 0; sl[0] = 0;
    #pragma unroll
    for (int s=0;s<NSP;s++){ a += (int)(((cnt[s]+127u)>>7)<<7); sl[s+1] = a; }
    if (blockIdx.x == 0){
      #pragma unroll
      for (int s=0;s<=NSP;s++) gstarts[s] = sl[s];
    }
  }
  __syncthreads();
  int i = blockIdx.x*256 + t;
  int s = sym[i];
  int lane = t & 63;
  #pragma unroll
  for (int ss=0; ss<NSP; ss++){
    unsigned long long m = __ballot(s==ss);
    if (s == ss){
      int leader = __builtin_ctzll(m);
      int cw = __popcll(m);
      unsigned int b = 0;
      if (lane == leader) b = atomicAdd(&cur[ss], (unsigned int)cw);
      b = (unsigned int)__shfl((int)b, leader);
      int rank = __popcll(m & ((1ull<<lane) - 1ull));
      sorted[sl[ss] + (int)b + rank] = i;
    }
  }
}

// weight prep via 32x32 LDS transpose tiles: coalesced reads AND writes
// grid: 4 species x 11 j-tiles x 8 i-tiles = 352 blocks x 256 thr
__global__ void k_prepw2(const void* __restrict__ W1, const void* __restrict__ b1,
                         const void* __restrict__ W2, const unsigned int* __restrict__ flag,
                         unsigned short* __restrict__ w1t, unsigned short* __restrict__ w1p,
                         float* __restrict__ b1p, float* __restrict__ w2p){
  __shared__ unsigned short T[32][36];
  const int isbf = (int)flag[0];
  const int bid = blockIdx.x;
  const int s  = bid / 88;
  const int jt = (bid % 88) / 8;
  const int it = bid % 8;
  const int t = threadIdx.x;
  {
    const int il = t >> 3;            // 0..31
    const int j4 = (t & 7) * 4;
    const int i = it*32 + il;
    #pragma unroll
    for (int e=0;e<4;e++){
      int j = jt*32 + j4 + e;
      float v = (j < HDIM) ? ldf(W1, (s*NO + i)*HDIM + j, isbf) : 0.f;
      T[il][j4+e] = f2bf(v);
    }
  }
  __syncthreads();
  {
    const int jl = t >> 3;
    const int i4 = (t & 7) * 4;
    ushort4 v; v.x = T[i4][jl]; v.y = T[i4+1][jl]; v.z = T[i4+2][jl]; v.w = T[i4+3][jl];
    *(ushort4*)&w1t[(s*HP + jt*32 + jl)*NO + it*32 + i4] = v;
    const int il = t >> 3;
    const int j4 = (t & 7) * 4;
    ushort4 u; u.x = T[il][j4]; u.y = T[il][j4+1]; u.z = T[il][j4+2]; u.w = T[il][j4+3];
    *(ushort4*)&w1p[(s*NO + it*32 + il)*HP + jt*32 + j4] = u;
  }
  if (it == 0 && t < 32){
    int j = jt*32 + t;
    b1p[s*HP + j] = (j < HDIM) ? ldf(b1, s*HDIM + j, isbf) : 0.f;
    w2p[s*HP + j] = (j < HDIM) ? ldf(W2, s*HDIM + j, isbf) : 0.f;
  }
}

// Fused per-tile kernel v7 = R12 v5 (103us known-good) + A-frag software prefetch
// + direct d_out writes (en/E/forces; no k_out pass).
// GEMM1': pre^T[352][128] = W1T x feat^T (K=256, 8 k-steps); waves 0-5 x3 frags,
//   6-7 x2 (22). acc[3][8]=96. GEMM2': dfeat^T[256][128] (K=352, 11 k-steps),
//   2 i-frags/wave, acc2[2][8]=64.
// MFMA C/D layout (HW-verified r3 probe): reg q of lane l -> row=(l>>4)*4+q, col=l&15.
__global__ __launch_bounds__(512,2) void k_main(
    const int* __restrict__ sorted, const int* __restrict__ starts,
    const void* __restrict__ pos, const void* __restrict__ Wd,
    const unsigned short* __restrict__ W1T, const unsigned short* __restrict__ W1P,
    const float* __restrict__ b1p, const float* __restrict__ w2p,
    const void* __restrict__ b2g, const int* __restrict__ crys,
    const unsigned int* __restrict__ flag, float* __restrict__ dout)
{
  extern __shared__ char smem[];
  ushort4* wdT = (ushort4*)smem;               // [256]
  char* featB  = smem + 2048;                  // bf16 [128] rows x 512B, XOR-swz
  char* dpB    = smem + 2048 + 65536;          // bf16 [128] rows x 720B
  float* Epart = (float*)dpB;                  // overlay after GEMM2: [8][128]
  float* Fpart = (float*)(dpB + 4096);         // overlay: [8][128][3]

  const int base = blockIdx.x*128;
  if (base >= starts[4]) return;
  const int isbf = (int)flag[0];
  int sp = 0;
  #pragma unroll
  for (int s=1;s<NSP;s++) sp = (base >= starts[s]) ? s : sp;

  const int tid = threadIdx.x;
  const int l = tid & 63;
  const int w = tid >> 6;       // 0..7
  const int c = l & 15;
  const int g = l >> 4;

  if (tid < 256){
    float x = ldf(Wd, tid, isbf), y = ldf(Wd, NO+tid, isbf), z = ldf(Wd, 2*NO+tid, isbf);
    ushort4 u; u.x = f2bf(x); u.y = f2bf(y); u.z = f2bf(z); u.w = 0;
    wdT[tid] = u;
  }
  __syncthreads();

  // ---- phase 1: stage feat tile (row m=tid&127, 64-col quarter h=tid>>7) ----
  // wdT reads are wave-uniform in h -> broadcast, conflict-free (r16 lesson).
  {
    const int m = tid & 127;
    const int h = tid >> 7;     // 0..3
    int a = sorted[base + m];
    float px=0.f, py=0.f, pz=0.f;
    if (a >= 0){ px = ldf(pos,3*a,isbf); py = ldf(pos,3*a+1,isbf); pz = ldf(pos,3*a+2,isbf); }
    const int swz = (m&7)<<4;
    char* rowp = featB + m*512;
    #pragma unroll
    for (int k8=0;k8<8;k8++){
      int i0 = h*64 + k8*8;
      unsigned int pk[4];
      #pragma unroll
      for (int p2=0;p2<4;p2++){
        unsigned short hv[2];
        #pragma unroll
        for (int e2=0;e2<2;e2++){
          ushort4 wv = wdT[i0 + 2*p2 + e2];
          float v = px*bf2f(wv.x) + py*bf2f(wv.y) + pz*bf2f(wv.z);
          float e = __expf(2.f*v);
          hv[e2] = f2bf(1.f - 2.f*rcpf(e+1.f));   // tanh via rcp
        }
        pk[p2] = (unsigned int)hv[0] | ((unsigned int)hv[1]<<16);
      }
      *(uint4*)(rowp + ((i0*2) ^ swz)) = make_uint4(pk[0],pk[1],pk[2],pk[3]);
    }
  }
  __syncthreads();

  // ---- phase 2: GEMM1 with A-frag prefetch (j-frags: waves 0-5 x3, 6-7 x2) ----
  const unsigned short* W1Ts = W1T + sp*HP*NO;
  const int fr0 = (w<6) ? w*3 : 18 + (w-6)*2;
  const int nT  = (w<6) ? 3 : 2;
  f32x4 acc[3][8];
  #pragma unroll
  for (int t=0;t<3;t++)
    #pragma unroll
    for (int nb=0;nb<8;nb++) acc[t][nb] = f32x4{0.f,0.f,0.f,0.f};

  short8 pf[3];
  #pragma unroll
  for (int t=0;t<3;t++)
    if (t < nT) pf[t] = *(const short8*)((const char*)W1Ts + ((fr0+t)*16 + c)*512 + g*16);

  #pragma unroll
  for (int kk=0; kk<8; kk++){
    short8 cur[3];
    #pragma unroll
    for (int t=0;t<3;t++) cur[t] = pf[t];
    if (kk < 7){
      #pragma unroll
      for (int t=0;t<3;t++)
        if (t < nT) pf[t] = *(const short8*)((const char*)W1Ts + ((fr0+t)*16 + c)*512 + (kk+1)*64 + g*16);
    }
    short8 bfr[8];
    #pragma unroll
    for (int nb=0;nb<8;nb++){
      int m = nb*16 + c;
      bfr[nb] = *(const short8*)(featB + m*512 + ((kk*64 + g*16) ^ ((m&7)<<4)));
    }
    #pragma unroll
    for (int t=0;t<3;t++){
      if (t < nT){
        #pragma unroll
        for (int nb=0;nb<8;nb++)
          acc[t][nb] = __builtin_amdgcn_mfma_f32_16x16x32_bf16(cur[t], bfr[nb], acc[t][nb], 0,0,0);
      }
    }
  }

  // ---- epilogue 1: silu, E partials (regs), dpre -> dpB ----
  const float* b1s = b1p + sp*HP;
  const float* w2s = w2p + sp*HP;
  float esp[8] = {0.f,0.f,0.f,0.f,0.f,0.f,0.f,0.f};
  #pragma unroll
  for (int t=0;t<3;t++){
    if (t < nT){
      const int j0 = (fr0+t)*16 + g*4;
      const float4 b1v = *(const float4*)(b1s + j0);
      const float4 w2v = *(const float4*)(w2s + j0);
      const float* b1a = (const float*)&b1v;
      const float* w2a = (const float*)&w2v;
      #pragma unroll
      for (int nb=0;nb<8;nb++){
        const int m = nb*16 + c;
        unsigned short dph[4];
        #pragma unroll
        for (int q=0;q<4;q++){
          float pre = acc[t][nb][q] + b1a[q];
          float sg = rcpf(1.f + __expf(-pre));     // sigmoid via rcp
          float h = pre*sg;
          esp[nb] += h*w2a[q];
          float dsl = sg*(1.f + pre*(1.f - sg));   // silu'
          dph[q] = f2bf(w2a[q]*dsl);               // dpre
        }
        *(uint2*)(dpB + m*DP_STRIDE + j0*2) =
            make_uint2((unsigned)dph[0] | ((unsigned)dph[1]<<16),
                       (unsigned)dph[2] | ((unsigned)dph[3]<<16));
      }
    }
  }
  float e8[8];
  #pragma unroll
  for (int nb=0;nb<8;nb++){
    float e = esp[nb];
    e += __shfl_xor(e, 16);
    e += __shfl_xor(e, 32);
    e8[nb] = e;                 // valid at g==0
  }
  __syncthreads();   // dpB complete

  // ---- phase 3: GEMM2 with A-frag prefetch (2 i-frags/wave) ----
  const unsigned short* W1Ps = W1P + sp*NO*HP;
  f32x4 acc2[2][8];
  #pragma unroll
  for (int t2=0;t2<2;t2++)
    #pragma unroll
    for (int nb=0;nb<8;nb++) acc2[t2][nb] = f32x4{0.f,0.f,0.f,0.f};

  short8 pf2[2];
  #pragma unroll
  for (int t2=0;t2<2;t2++)
    pf2[t2] = *(const short8*)((const char*)W1Ps + ((2*w+t2)*16 + c)*704 + g*16);

  #pragma unroll
  for (int kk=0; kk<11; kk++){
    short8 cur2[2];
    #pragma unroll
    for (int t2=0;t2<2;t2++) cur2[t2] = pf2[t2];
    if (kk < 10){
      #pragma unroll
      for (int t2=0;t2<2;t2++)
        pf2[t2] = *(const short8*)((const char*)W1Ps + ((2*w+t2)*16 + c)*704 + (kk+1)*64 + g*16);
    }
    short8 bfr[8];
    #pragma unroll
    for (int nb=0;nb<8;nb++){
      int m = nb*16 + c;
      bfr[nb] = *(const short8*)(dpB + m*DP_STRIDE + kk*64 + g*16);
    }
    #pragma unroll
    for (int t2=0;t2<2;t2++){
      #pragma unroll
      for (int nb=0;nb<8;nb++)
        acc2[t2][nb] = __builtin_amdgcn_mfma_f32_16x16x32_bf16(cur2[t2], bfr[nb], acc2[t2][nb], 0,0,0);
    }
  }

  // ---- epilogue 2: dpos = (dfeat * (1-feat^2)) @ Wd^T (featB still alive) ----
  float fax[8], fay[8], faz[8];
  #pragma unroll
  for (int nb=0;nb<8;nb++){ fax[nb]=0.f; fay[nb]=0.f; faz[nb]=0.f; }
  #pragma unroll
  for (int t2=0;t2<2;t2++){
    const int i0 = (2*w+t2)*16 + g*4;
    #pragma unroll
    for (int nb=0;nb<8;nb++){
      const int m = nb*16 + c;
      uint2 fpk = *(const uint2*)(featB + m*512 + ((i0*2) ^ ((m&7)<<4)));
      unsigned short fh[4];
      fh[0] = (unsigned short)(fpk.x & 0xffffu); fh[1] = (unsigned short)(fpk.x >> 16);
      fh[2] = (unsigned short)(fpk.y & 0xffffu); fh[3] = (unsigned short)(fpk.y >> 16);
      #pragma unroll
      for (int q=0;q<4;q++){
        float ff = bf2f(fh[q]);
        float gsc = acc2[t2][nb][q] * (1.f - ff*ff);
        ushort4 wv = wdT[i0 + q];
        fax[nb] += gsc*bf2f(wv.x);
        fay[nb] += gsc*bf2f(wv.y);
        faz[nb] += gsc*bf2f(wv.z);
      }
    }
  }
  #pragma unroll
  for (int nb=0;nb<8;nb++){
    float x = fax[nb], y = fay[nb], z = faz[nb];
    x += __shfl_xor(x, 16); x += __shfl_xor(x, 32);
    y += __shfl_xor(y, 16); y += __shfl_xor(y, 32);
    z += __shfl_xor(z, 16); z += __shfl_xor(z, 32);
    fax[nb] = x; fay[nb] = y; faz[nb] = z;
  }
  __syncthreads();   // all waves done with dpB -> overlay Epart/Fpart

  if (g == 0){
    #pragma unroll
    for (int nb=0;nb<8;nb++){
      const int m = nb*16 + c;
      Epart[w*128 + m] = e8[nb];
      Fpart[(w*128 + m)*3 + 0] = fax[nb];
      Fpart[(w*128 + m)*3 + 1] = fay[nb];
      Fpart[(w*128 + m)*3 + 2] = faz[nb];
    }
  }
  __syncthreads();

  // ---- final: first 128 threads sum 8 wave-partials, write d_out directly ----
  if (tid < 128){
    int a = sorted[base + tid];
    if (a >= 0){
      float E = ldf(b2g, sp, isbf);
      float fx = 0.f, fy = 0.f, fz = 0.f;
      #pragma unroll
      for (int ww=0; ww<8; ww++){
        E  += Epart[ww*128 + tid];
        fx += Fpart[(ww*128 + tid)*3 + 0];
        fy += Fpart[(ww*128 + tid)*3 + 1];
        fz += Fpart[(ww*128 + tid)*3 + 2];
      }
      dout[a] = E;                          // en
      atomicAdd(&dout[NTA + crys[a]], E);   // E (zeroed by k_init2 each call)
      dout[NTA + NC + 3*a + 0] = fx;        // forces
      dout[NTA + NC + 3*a + 1] = fy;
      dout[NTA + NC + 3*a + 2] = fz;
    }
  }
}

extern "C" void kernel_launch(void* const* d_in, const int* in_sizes, int n_in,
                              void* d_out, int out_size, void* d_ws, size_t ws_size,
                              hipStream_t stream) {
  const int*   symbols    = (const int*)  d_in[0];
  const void*  positions  = d_in[1];
  // d_in[2] cells, d_in[3] pbcs, d_in[4] energyidx: unused by the math
  const int*   crystalidx = (const int*)  d_in[5];
  const void*  Wd         = d_in[6];
  const void*  W1         = d_in[7];
  const void*  b1         = d_in[8];
  const void*  W2         = d_in[9];
  const void*  b2         = d_in[10];
  float* dout = (float*)d_out;   // f32 output buffer

  char* ws = (char*)d_ws;
  unsigned int* cnt    = (unsigned int*)(ws + OFF_CNT);
  unsigned int* cur    = (unsigned int*)(ws + OFF_CUR);
  int*          starts = (int*)         (ws + OFF_START);
  unsigned int* flag   = (unsigned int*)(ws + OFF_FLAG);
  int*          sorted = (int*)         (ws + OFF_SORT);
  float*        b1p    = (float*)       (ws + OFF_B1P);
  float*        w2p    = (float*)       (ws + OFF_W2P);
  unsigned short* w1t  = (unsigned short*)(ws + OFF_W1T);
  unsigned short* w1pp = (unsigned short*)(ws + OFF_W1P);

  hipFuncSetAttribute((const void*)k_main,
                      hipFuncAttributeMaxDynamicSharedMemorySize, LDS_MAIN);

  hipMemsetAsync(ws, 0, 256, stream);                 // cnt/cur/starts/flag
  k_init2   <<<258, 256, 0, stream>>>(symbols, cnt, sorted,
                                      (const unsigned short*)positions, flag, dout);
  k_scatter2<<<256, 256, 0, stream>>>(symbols, cnt, cur, sorted, starts);
  k_prepw2  <<<352, 256, 0, stream>>>(W1, b1, W2, flag, w1t, w1pp, b1p, w2p);
  k_main    <<<516, 512, LDS_MAIN, stream>>>(sorted, starts, positions, Wd,
                                             w1t, w1pp, b1p, w2p, b2, crystalidx,
                                             flag, dout);
}